// Round 1
// baseline (255.750 us; speedup 1.0000x reference)
//
#include <hip/hip_runtime.h>

// LIF scan over T=16: mem_t = beta*mem + x_t - spk_{t-1}; spk_t = (mem_t - 1) > 0.
// Neurons independent -> 1 thread owns 4 neurons across all T.
//
// R4: R3's 3-phase structure (16 prefetch loads / register recurrence / 16 NT
// stores) was being DEFEATED by the machine scheduler: VGPR_Count=36 proves the
// 16 f4 loads (64 VGPRs min) were sunk back into the recurrence, capping
// per-wave MLP at ~4 outstanding loads -> 3.15 TB/s combined (half the float4
// copy ceiling), VALUBusy 4%. Fix: __builtin_amdgcn_sched_barrier(0) fences at
// both phase boundaries. vmcnt retires in order, so compute step t waits only
// for load t while t+1..15 remain in flight (16 KB in flight per wave).

constexpr int   T      = 16;
constexpr float BETA   = 0.9f;
constexpr float THRESH = 1.0f;

typedef float f4 __attribute__((ext_vector_type(4)));

__global__ __launch_bounds__(256) void lif_kernel(const float* __restrict__ x,
                                                  float* __restrict__ out,
                                                  int n_per_t) {
    // No FMA contraction: must match numpy's two-rounding fp32 exactly, else
    // ~1-ulp drift flips spikes at the threshold (absmax = 1.0 cascades).
#pragma clang fp contract(off)
    const int idx = (blockIdx.x * blockDim.x + threadIdx.x) * 4;
    if (idx >= n_per_t) return;

    f4 v[T];  // holds x_t on the way in, spk_t on the way out

    // Phase 1: 16 independent loads issued back-to-back (coalesced per wave,
    // streams 8 MB apart). Must all be in flight before any compute.
#pragma unroll
    for (int t = 0; t < T; ++t) {
        v[t] = *reinterpret_cast<const f4*>(x + (size_t)t * (size_t)n_per_t + (size_t)idx);
    }
    // Fence: scheduler may not sink any load past this point (that is what
    // produced VGPR=36 / MLP~4 in R3). Costs ~64 VGPRs of live range -> ~4
    // waves/SIMD, same as the occupancy we measured anyway.
    __builtin_amdgcn_sched_barrier(0);

    // Phase 2: the sequential recurrence, pure registers. Use of v[t] forces
    // s_waitcnt vmcnt(15-t): incremental in-order drain, loads stay pipelined.
    f4 mem = (f4)(0.f);
    f4 spk = (f4)(0.f);
#pragma unroll
    for (int t = 0; t < T; ++t) {
#pragma unroll
        for (int j = 0; j < 4; ++j) {
            mem[j] = BETA * mem[j] + v[t][j] - spk[j] * THRESH;
            spk[j] = (mem[j] - THRESH) > 0.f ? 1.f : 0.f;
        }
        v[t] = spk;
    }

    // Fence: keep the store burst out of the compute chain.
    __builtin_amdgcn_sched_barrier(0);

    // Phase 3: 16 stores, nontemporal (output never re-read on device).
#pragma unroll
    for (int t = 0; t < T; ++t) {
        __builtin_nontemporal_store(v[t],
            reinterpret_cast<f4*>(out + (size_t)t * (size_t)n_per_t + (size_t)idx));
    }
}

extern "C" void kernel_launch(void* const* d_in, const int* in_sizes, int n_in,
                              void* d_out, int out_size, void* d_ws, size_t ws_size,
                              hipStream_t stream) {
    const float* x   = (const float*)d_in[0];
    float*       out = (float*)d_out;

    const int total   = in_sizes[0];      // 33,554,432
    const int n_per_t = total / T;        // 2,097,152 (divisible by 4)
    const int threads = n_per_t / 4;      // 524,288

    dim3 block(256);
    dim3 grid((threads + block.x - 1) / block.x);  // 2048 blocks
    lif_kernel<<<grid, block, 0, stream>>>(x, out, n_per_t);
}

// Round 2
// 241.978 us; speedup vs baseline: 1.0569x; 1.0569x over previous
//
#include <hip/hip_runtime.h>

// LIF scan over T=16: mem_t = beta*mem + x_t - spk_{t-1}; spk_t = (mem_t - 1) > 0.
// Neurons independent -> 1 thread owns 4 neurons across all T.
//
// R5: R3/R4 post-mortem: VGPR_Count=36 in BOTH rounds proves the 16-load
// prefetch never existed in the final code (16 live f4 = 64 distinct VGPRs
// minimum, since vmcnt returns in order and a pending-load dest can't be
// overwritten before use). sched_barrier(0) is inaccessible-mem, so readonly
// loads legally sank across it (and the fractured regions cost 25%).
// Fix: a DATA dependency no pass can break — asm volatile with all 16 f4s as
// "+v" in-out operands between load phase and compute phase. Forces: 16 loads
// issued back-to-back, 16 distinct register quads, one vmcnt(0) drain with
// 16 KB in flight per wave. launch_bounds(256,4) caps the allocator at 128
// VGPR (4 waves/EU = the 16 waves/CU we already measure) so it doesn't spill
// the prefetch chasing default occupancy targets.

constexpr int   T      = 16;
constexpr float BETA   = 0.9f;
constexpr float THRESH = 1.0f;

typedef float f4 __attribute__((ext_vector_type(4)));

__global__ __launch_bounds__(256, 4) void lif_kernel(const float* __restrict__ x,
                                                     float* __restrict__ out,
                                                     int n_per_t) {
    // No FMA contraction: must match numpy's two-rounding fp32 exactly, else
    // ~1-ulp drift flips spikes at the threshold (absmax = 1.0 cascades).
#pragma clang fp contract(off)
    const int idx = (blockIdx.x * blockDim.x + threadIdx.x) * 4;
    if (idx >= n_per_t) return;

    f4 v[T];  // holds x_t on the way in, spk_t on the way out

    // Phase 1: 16 independent loads issued back-to-back (coalesced per wave,
    // streams 8 MB apart).
#pragma unroll
    for (int t = 0; t < T; ++t) {
        v[t] = *reinterpret_cast<const f4*>(x + (size_t)t * (size_t)n_per_t + (size_t)idx);
    }

    // Binding fence: every v[t] is an in-out operand, so (a) all 16 loads must
    // be issued and completed before this point (single vmcnt(0) drain, loads
    // fully pipelined), (b) all 16 live simultaneously -> 64 distinct VGPRs,
    // (c) nothing can fold a load past this into the recurrence.
    asm volatile("" : "+v"(v[0]), "+v"(v[1]), "+v"(v[2]), "+v"(v[3]),
                      "+v"(v[4]), "+v"(v[5]), "+v"(v[6]), "+v"(v[7]),
                      "+v"(v[8]), "+v"(v[9]), "+v"(v[10]), "+v"(v[11]),
                      "+v"(v[12]), "+v"(v[13]), "+v"(v[14]), "+v"(v[15]));

    // Phase 2: the sequential recurrence, pure registers.
    f4 mem = (f4)(0.f);
    f4 spk = (f4)(0.f);
#pragma unroll
    for (int t = 0; t < T; ++t) {
#pragma unroll
        for (int j = 0; j < 4; ++j) {
            mem[j] = BETA * mem[j] + v[t][j] - spk[j] * THRESH;
            spk[j] = (mem[j] - THRESH) > 0.f ? 1.f : 0.f;
        }
        v[t] = spk;
    }

    // Phase 3: 16 stores, nontemporal (output never re-read on device).
#pragma unroll
    for (int t = 0; t < T; ++t) {
        __builtin_nontemporal_store(v[t],
            reinterpret_cast<f4*>(out + (size_t)t * (size_t)n_per_t + (size_t)idx));
    }
}

extern "C" void kernel_launch(void* const* d_in, const int* in_sizes, int n_in,
                              void* d_out, int out_size, void* d_ws, size_t ws_size,
                              hipStream_t stream) {
    const float* x   = (const float*)d_in[0];
    float*       out = (float*)d_out;

    const int total   = in_sizes[0];      // 33,554,432
    const int n_per_t = total / T;        // 2,097,152 (divisible by 4)
    const int threads = n_per_t / 4;      // 524,288

    dim3 block(256);
    dim3 grid((threads + block.x - 1) / block.x);  // 2048 blocks
    lif_kernel<<<grid, block, 0, stream>>>(x, out, n_per_t);
}